// Round 13
// baseline (704.342 us; speedup 1.0000x reference)
//
#include <hip/hip_runtime.h>
#include <math.h>

#define N_NODES 50000
#define N_EDGES 400000

typedef __bf16 bf16x8 __attribute__((ext_vector_type(8)));
typedef float f32x4 __attribute__((ext_vector_type(4)));

// ---- split-precision helpers: f32 <-> (hi bf16 | lo bf16) packed in u32 ----
__device__ __forceinline__ unsigned bf16_rne(float v) {
    unsigned u = __float_as_uint(v);
    return (u + 0x7FFFu + ((u >> 16) & 1u)) >> 16;
}
__device__ __forceinline__ unsigned pack_split(float v) {
    unsigned hi = bf16_rne(v);
    float hif = __uint_as_float(hi << 16);
    unsigned lo = bf16_rne(v - hif);
    return (hi << 16) | lo;
}
__device__ __forceinline__ float unpack_ps(unsigned w) {
    return __uint_as_float(w & 0xFFFF0000u) + __uint_as_float(w << 16);
}

// ================= CSR build =================
__global__ void k_zero_i(int* __restrict__ p, int n) {
    int i = blockIdx.x * blockDim.x + threadIdx.x;
    if (i < n) p[i] = 0;
}

__global__ void k_count(const int* __restrict__ dst, int* __restrict__ cnt) {
    int e = blockIdx.x * blockDim.x + threadIdx.x;
    if (e < N_EDGES) atomicAdd(&cnt[dst[e]], 1);
}

__global__ __launch_bounds__(1024) void k_scan(const int* __restrict__ cnt,
                                               int* __restrict__ rowptr,
                                               float* __restrict__ dinv, int n) {
    __shared__ int sm[1024];
    __shared__ int carry;
    if (threadIdx.x == 0) carry = 0;
    __syncthreads();
    for (int base = 0; base < n; base += 1024) {
        int i = base + threadIdx.x;
        int v = (i < n) ? cnt[i] : 0;
        sm[threadIdx.x] = v;
        __syncthreads();
        for (int off = 1; off < 1024; off <<= 1) {
            int t = (threadIdx.x >= (unsigned)off) ? sm[threadIdx.x - off] : 0;
            __syncthreads();
            sm[threadIdx.x] += t;
            __syncthreads();
        }
        if (i < n) {
            rowptr[i] = carry + sm[threadIdx.x] - v;
            dinv[i] = rsqrtf((float)(v + 1));
        }
        __syncthreads();
        if (threadIdx.x == 0) carry += sm[1023];
        __syncthreads();
    }
    if (threadIdx.x == 0) rowptr[n] = carry;
}

__global__ void k_copy_i(const int* __restrict__ s, int* __restrict__ d, int n) {
    int i = blockIdx.x * blockDim.x + threadIdx.x;
    if (i < n) d[i] = s[i];
}

__global__ void k_fill(const int* __restrict__ src, const int* __restrict__ dst,
                       int* __restrict__ cursor, int* __restrict__ csr) {
    int e = blockIdx.x * blockDim.x + threadIdx.x;
    if (e >= N_EDGES) return;
    int d = dst[e];
    int pos = atomicAdd(&cursor[d], 1);
    csr[pos] = src[e];
}

// ================= weight prep: W[K][N] f32 -> Wt[N][K] packed =================
__global__ void k_wprep(const float* __restrict__ W, unsigned* __restrict__ Wtp, int K, int N) {
    int i = blockIdx.x * blockDim.x + threadIdx.x;
    if (i >= K * N) return;
    int k = i / N, n = i % N;
    Wtp[(size_t)n * K + k] = pack_split(W[i]);
}

// ================= xs = dinv[i] * x (f32) =================
__global__ void k_rowscale(const float* __restrict__ x, const float* __restrict__ dinv,
                           float* __restrict__ xs) {
    int idx = blockIdx.x * blockDim.x + threadIdx.x;
    if (idx >= N_NODES * 32) return;
    int i = idx >> 5;
    float4 v = ((const float4*)x)[idx];
    float s = dinv[i];
    v.x *= s; v.y *= s; v.z *= s; v.w *= s;
    ((float4*)xs)[idx] = v;
}

// ================= CSR aggregation =================
template <int VEC, int MODE, int INP, int OUTP>
__global__ __launch_bounds__(256) void k_agg(
    const void* __restrict__ gv, const int* __restrict__ rowptr,
    const int* __restrict__ csr, const float* __restrict__ dinv,
    const float* __restrict__ bias, void* __restrict__ ov)
{
    constexpr int W = 64 * VEC;
    const int wave = threadIdx.x >> 6, lane = threadIdx.x & 63;
    const int node = blockIdx.x * 4 + wave;
    if (node >= N_NODES) return;
    const int col = lane * VEC;

    float acc[VEC];
#pragma unroll
    for (int v = 0; v < VEC; ++v) acc[v] = 0.f;

    auto fetch_add = [&](int r) {
        if constexpr (INP) {
            const unsigned* p = (const unsigned*)gv + (size_t)r * W + col;
            if constexpr (VEC == 4) {
                uint4 t = *(const uint4*)p;
                acc[0] += unpack_ps(t.x); acc[1] += unpack_ps(t.y);
                acc[2] += unpack_ps(t.z); acc[3] += unpack_ps(t.w);
            } else if constexpr (VEC == 2) {
                uint2 t = *(const uint2*)p;
                acc[0] += unpack_ps(t.x); acc[1] += unpack_ps(t.y);
            } else acc[0] += unpack_ps(*p);
        } else {
            const float* p = (const float*)gv + (size_t)r * W + col;
            if constexpr (VEC == 4) {
                float4 t = *(const float4*)p;
                acc[0] += t.x; acc[1] += t.y; acc[2] += t.z; acc[3] += t.w;
            } else if constexpr (VEC == 2) {
                float2 t = *(const float2*)p;
                acc[0] += t.x; acc[1] += t.y;
            } else acc[0] += *(const float*)p;
        }
    };

    fetch_add(node);
    const int beg = rowptr[node], end = rowptr[node + 1];
    for (int j = beg; j < end; ++j) fetch_add(csr[j]);

    const float sc = dinv[node];
    float r[VEC];
#pragma unroll
    for (int v = 0; v < VEC; ++v) {
        float t = sc * acc[v];
        if (MODE == 1) t = fmaxf(t + bias[col + v], 0.f);
        r[v] = t;
    }
    if constexpr (OUTP) {
        unsigned* po = (unsigned*)ov + (size_t)node * W + col;
        if constexpr (VEC == 4)
            *(uint4*)po = make_uint4(pack_split(r[0]), pack_split(r[1]), pack_split(r[2]), pack_split(r[3]));
        else if constexpr (VEC == 2)
            *(uint2*)po = make_uint2(pack_split(r[0]), pack_split(r[1]));
        else *po = pack_split(r[0]);
    } else {
        float* po = (float*)ov + (size_t)node * W + col;
        if constexpr (VEC == 4) *(float4*)po = make_float4(r[0], r[1], r[2], r[3]);
        else if constexpr (VEC == 2) *(float2*)po = make_float2(r[0], r[1]);
        else *po = r[0];
    }
}

__global__ void k_agg2(const float* __restrict__ g, const int* __restrict__ rowptr,
                       const int* __restrict__ csr, const float* __restrict__ dinv,
                       float* __restrict__ o) {
    int i = blockIdx.x * blockDim.x + threadIdx.x;
    if (i >= N_NODES) return;
    float2 a = *(const float2*)&g[2 * (size_t)i];
    int beg = rowptr[i], end = rowptr[i + 1];
    for (int j = beg; j < end; ++j) {
        int s = csr[j];
        float2 t = *(const float2*)&g[2 * (size_t)s];
        a.x += t.x; a.y += t.y;
    }
    float sc = dinv[i];
    o[2 * (size_t)i + 0] = sc * a.x;
    o[2 * (size_t)i + 1] = sc * a.y;
}

// ================= split-bf16 MFMA GEMM, 2-phase pipelined =================
// A (packed [M][K]) @ Wt (packed [N][K]) -> Gp (packed [M][N]).
// Block: BM=2*WM x BN=2*WN, 256 threads = 4 waves in 2x2; wave owns WM x WN.
// BK=32; hi*hi + hi*lo + lo*hi (f32-level accuracy).
// Pipeline (T3-min): double-buffered LDS; per K-step:
//   issue loads(t+1) -> regs | frag-read + MFMA on buf[cur] | commit regs->buf[cur^1]
//   | ONE barrier.  Load latency hides under MFMA; barrier count halved.
// Grid: blockIdx.x = column group, blockIdx.y = row stripe (A-stripe L2/L3 reuse).
// mode 0: dinv[r]*acc; 1: relu(acc+bias); 2: dinv[r]*relu(acc+bias)
template <int WM, int WN>
__global__ __launch_bounds__(256) void k_gemm_mfma(
    const unsigned* __restrict__ Ap, const unsigned* __restrict__ Wtp,
    const float* __restrict__ dinv, const float* __restrict__ bias,
    unsigned* __restrict__ Gp, int M, int K, int N, int mode)
{
    constexpr int BM = 2 * WM, BN = 2 * WN;
    constexpr int AF = WM / 16, BF = WN / 16;
    constexpr int ACH = BM / 32, BCH = BN / 32;   // uint4 chunks per thread
    constexpr int BUF = (2 * BM + 2 * BN) * 64;   // bytes per LDS buffer
    __shared__ char lds[2 * BUF];

    const int tid = threadIdx.x;
    const int m0 = blockIdx.y * BM;
    const int n0 = blockIdx.x * BN;
    const int wv = tid >> 6, l = tid & 63;
    const int wr = wv >> 1, wc = wv & 1;
    const int lr = l & 15, ls = l >> 4;

    // fragment read offsets, relative to buffer base (Ahi at 0, B rel. own base)
    int aoff[AF], boff[BF];
#pragma unroll
    for (int f = 0; f < AF; ++f) {
        int row = wr * WM + f * 16 + lr;
        aoff[f] = (row * 64 + ls * 16) ^ ((row & 7) << 4);
    }
#pragma unroll
    for (int j = 0; j < BF; ++j) {
        int row = wc * WN + j * 16 + lr;
        boff[j] = (row * 64 + ls * 16) ^ ((row & 7) << 4);
    }

    uint4 ra[ACH], rb[BCH];   // staging registers (in flight across MFMA)

    auto issue = [&](int kt) {
#pragma unroll
        for (int p = 0; p < ACH; ++p) {
            int c = p * 256 + tid;
            int row = c >> 3, c4 = (c & 7) << 2;
            int grow = m0 + row;
            ra[p] = make_uint4(0u, 0u, 0u, 0u);
            if (grow < M) ra[p] = *(const uint4*)&Ap[(size_t)grow * K + kt + c4];
        }
#pragma unroll
        for (int p = 0; p < BCH; ++p) {
            int c = p * 256 + tid;
            int row = c >> 3, c4 = (c & 7) << 2;
            rb[p] = *(const uint4*)&Wtp[(size_t)(n0 + row) * K + kt + c4];
        }
    };

    auto commit = [&](int buf) {
        char* Ahi = lds + buf * BUF;
        char* Alo = Ahi + BM * 64;
        char* Bhi = Alo + BM * 64;
        char* Blo = Bhi + BN * 64;
#pragma unroll
        for (int p = 0; p < ACH; ++p) {
            int c = p * 256 + tid;
            int row = c >> 3, c4 = (c & 7) << 2;
            uint4 w = ra[p];
            ushort4 hi, lo;
            hi.x = w.x >> 16; lo.x = w.x & 0xFFFFu;
            hi.y = w.y >> 16; lo.y = w.y & 0xFFFFu;
            hi.z = w.z >> 16; lo.z = w.z & 0xFFFFu;
            hi.w = w.w >> 16; lo.w = w.w & 0xFFFFu;
            int off = (row * 64 + c4 * 2) ^ ((row & 7) << 4);
            *(ushort4*)(Ahi + off) = hi;
            *(ushort4*)(Alo + off) = lo;
        }
#pragma unroll
        for (int p = 0; p < BCH; ++p) {
            int c = p * 256 + tid;
            int row = c >> 3, c4 = (c & 7) << 2;
            uint4 w = rb[p];
            ushort4 hi, lo;
            hi.x = w.x >> 16; lo.x = w.x & 0xFFFFu;
            hi.y = w.y >> 16; lo.y = w.y & 0xFFFFu;
            hi.z = w.z >> 16; lo.z = w.z & 0xFFFFu;
            hi.w = w.w >> 16; lo.w = w.w & 0xFFFFu;
            int off = (row * 64 + c4 * 2) ^ ((row & 7) << 4);
            *(ushort4*)(Bhi + off) = hi;
            *(ushort4*)(Blo + off) = lo;
        }
    };

    f32x4 acc[AF][BF] = {};
    const int nt = K / 32;

    issue(0);
    commit(0);
    __syncthreads();
    int cur = 0;

    for (int t = 0; t < nt; ++t) {
        if (t + 1 < nt) issue((t + 1) * 32);   // loads in flight during MFMA

        const char* base = lds + cur * BUF;
        bf16x8 ah[AF], al[AF], bh[BF], bl[BF];
#pragma unroll
        for (int f = 0; f < AF; ++f) {
            ah[f] = *(const bf16x8*)(base + aoff[f]);
            al[f] = *(const bf16x8*)(base + BM * 64 + aoff[f]);
        }
#pragma unroll
        for (int j = 0; j < BF; ++j) {
            bh[j] = *(const bf16x8*)(base + 2 * BM * 64 + boff[j]);
            bl[j] = *(const bf16x8*)(base + 2 * BM * 64 + BN * 64 + boff[j]);
        }
#pragma unroll
        for (int f = 0; f < AF; ++f)
#pragma unroll
            for (int j = 0; j < BF; ++j) {
                acc[f][j] = __builtin_amdgcn_mfma_f32_16x16x32_bf16(ah[f], bh[j], acc[f][j], 0, 0, 0);
                acc[f][j] = __builtin_amdgcn_mfma_f32_16x16x32_bf16(ah[f], bl[j], acc[f][j], 0, 0, 0);
                acc[f][j] = __builtin_amdgcn_mfma_f32_16x16x32_bf16(al[f], bh[j], acc[f][j], 0, 0, 0);
            }

        if (t + 1 < nt) {
            commit(cur ^ 1);      // vmcnt wait on ra/rb happens here
            __syncthreads();      // single barrier per K-step
            cur ^= 1;
        }
    }

    // ---- epilogue: frag (f,j): row = m0+wr*WM+f*16+ls*4+reg, col = n0+wc*WN+j*16+lr ----
#pragma unroll
    for (int f = 0; f < AF; ++f)
#pragma unroll
        for (int j = 0; j < BF; ++j) {
            int col = n0 + wc * WN + j * 16 + lr;
            float bc = (mode >= 1) ? bias[col] : 0.f;
#pragma unroll
            for (int reg = 0; reg < 4; ++reg) {
                int r = m0 + wr * WM + f * 16 + ls * 4 + reg;
                if (r < M) {
                    float t = acc[f][j][reg];
                    if (mode == 0)      t = dinv[r] * t;
                    else if (mode == 1) t = fmaxf(t + bc, 0.f);
                    else                t = dinv[r] * fmaxf(t + bc, 0.f);
                    Gp[(size_t)r * N + col] = pack_split(t);
                }
            }
        }
}

// ================= last-layer GEMM: K=64, N=2, f32 =================
__global__ void k_gemm2(const float* __restrict__ A, const float* __restrict__ W,
                        const float* __restrict__ dinv, float* __restrict__ G, int M, int K)
{
    int i = blockIdx.x * blockDim.x + threadIdx.x;
    if (i >= M) return;
    float a0 = 0.f, a1 = 0.f;
    for (int k = 0; k < K; k += 4) {
        float4 a = *(const float4*)&A[(size_t)i * K + k];
        a0 += a.x * W[(k + 0) * 2 + 0] + a.y * W[(k + 1) * 2 + 0]
            + a.z * W[(k + 2) * 2 + 0] + a.w * W[(k + 3) * 2 + 0];
        a1 += a.x * W[(k + 0) * 2 + 1] + a.y * W[(k + 1) * 2 + 1]
            + a.z * W[(k + 2) * 2 + 1] + a.w * W[(k + 3) * 2 + 1];
    }
    float s = dinv[i];
    G[2 * (size_t)i + 0] = s * a0;
    G[2 * (size_t)i + 1] = s * a1;
}

// ================= final: logits + b5 -> log_softmax =================
__global__ void k_final(const float* __restrict__ lg, const float* __restrict__ bias,
                        float* __restrict__ out, int M)
{
    int i = blockIdx.x * blockDim.x + threadIdx.x;
    if (i >= M) return;
    float o0 = lg[2 * (size_t)i + 0] + bias[0];
    float o1 = lg[2 * (size_t)i + 1] + bias[1];
    float m = fmaxf(o0, o1);
    float lse = m + logf(expf(o0 - m) + expf(o1 - m));
    out[2 * (size_t)i + 0] = o0 - lse;
    out[2 * (size_t)i + 1] = o1 - lse;
}

extern "C" void kernel_launch(void* const* d_in, const int* in_sizes, int n_in,
                              void* d_out, int out_size, void* d_ws, size_t ws_size,
                              hipStream_t stream) {
    const float* x   = (const float*)d_in[0];
    const int*   ei  = (const int*)d_in[1];
    const int*   src = ei;
    const int*   dst = ei + N_EDGES;
    const float* W1 = (const float*)d_in[2];  const float* b1 = (const float*)d_in[3];
    const float* W2 = (const float*)d_in[4];  const float* b2 = (const float*)d_in[5];
    const float* W3 = (const float*)d_in[6];  const float* b3 = (const float*)d_in[7];
    const float* W4 = (const float*)d_in[8];  const float* b4 = (const float*)d_in[9];
    const float* W5 = (const float*)d_in[10]; const float* b5 = (const float*)d_in[11];
    float* out = (float*)d_out;

    char* ws = (char*)d_ws;
    float*    dinv   = (float*)(ws + 0);
    int*      cnt    = (int*)(ws + 256 * 1024);
    int*      rowptr = (int*)(ws + 512 * 1024);
    int*      cursor = (int*)(ws + 768 * 1024);
    int*      csr    = (int*)(ws + 1024 * 1024);
    unsigned* wt1 = (unsigned*)(ws + 3 * 1024 * 1024);
    unsigned* wt2 = wt1 + 128 * 256;
    unsigned* wt3 = wt2 + 256 * 512;
    unsigned* wt4 = wt3 + 512 * 256;

    char* D = ws + 6 * 1024 * 1024;
    float*    xs   = (float*)D;                                    // [50000][128] f32
    unsigned* aggx = (unsigned*)(D + (size_t)N_NODES * 128 * 4);   // [50000][128] packed
    unsigned* h1s  = (unsigned*)(D + (size_t)N_NODES * 512 * 4);   // R1: [50000][256]
    unsigned* a2   = (unsigned*)(D + (size_t)N_NODES * 768 * 4);   // R2: [50000][256]
    unsigned* h2   = (unsigned*)D;                                 // R0: [50000][512]
    unsigned* g3s  = h1s;
    unsigned* h3   = a2;
    unsigned* g4s  = (unsigned*)D;                                 // [50000][64]
    float*    h4   = (float*)(D + (size_t)N_NODES * 64 * 4);       // [50000][64] f32
    float*    g5s  = (float*)(D + (size_t)N_NODES * 128 * 4);      // [50000][2]
    float*    lgt  = (float*)(D + (size_t)N_NODES * 132 * 4);      // [50000][2]

    const int T = 256;
    const int nodeB = (N_NODES + T - 1) / T;
    const int edgeB = (N_EDGES + T - 1) / T;
    const int aggB  = (N_NODES + 3) / 4;
    const int gy    = (N_NODES + 63) / 64;     // BM=64 row stripes (blockIdx.y)

    // ---- CSR + dinv + weight prep ----
    k_zero_i<<<nodeB, T, 0, stream>>>(cnt, N_NODES);
    k_count<<<edgeB, T, 0, stream>>>(dst, cnt);
    k_scan<<<1, 1024, 0, stream>>>(cnt, rowptr, dinv, N_NODES);
    k_copy_i<<<nodeB, T, 0, stream>>>(rowptr, cursor, N_NODES);
    k_fill<<<edgeB, T, 0, stream>>>(src, dst, cursor, csr);
    k_wprep<<<(128 * 256 + T - 1) / T, T, 0, stream>>>(W1, wt1, 128, 256);
    k_wprep<<<(256 * 512 + T - 1) / T, T, 0, stream>>>(W2, wt2, 256, 512);
    k_wprep<<<(512 * 256 + T - 1) / T, T, 0, stream>>>(W3, wt3, 512, 256);
    k_wprep<<<(256 * 64 + T - 1) / T, T, 0, stream>>>(W4, wt4, 256, 64);

    // ---- L1: agg(128) -> GEMM 128->256, h1s = dinv*relu(+b1) ----
    k_rowscale<<<(N_NODES * 32 + T - 1) / T, T, 0, stream>>>(x, dinv, xs);
    k_agg<2, 0, 0, 1><<<aggB, T, 0, stream>>>(xs, rowptr, csr, dinv, nullptr, aggx);
    k_gemm_mfma<32, 64><<<dim3(2, gy), T, 0, stream>>>(aggx, wt1, dinv, b1, h1s, N_NODES, 128, 256, 2);

    // ---- L2: agg(256) -> GEMM 256->512, h2 = relu(+b2) ----
    k_agg<4, 0, 1, 1><<<aggB, T, 0, stream>>>(h1s, rowptr, csr, dinv, nullptr, a2);
    k_gemm_mfma<32, 64><<<dim3(4, gy), T, 0, stream>>>(a2, wt2, dinv, b2, h2, N_NODES, 256, 512, 1);

    // ---- L3: GEMM 512->256 (g3s = dinv*acc) -> agg w/ relu+b3 ----
    k_gemm_mfma<32, 64><<<dim3(2, gy), T, 0, stream>>>(h2, wt3, dinv, nullptr, g3s, N_NODES, 512, 256, 0);
    k_agg<4, 1, 1, 1><<<aggB, T, 0, stream>>>(g3s, rowptr, csr, dinv, b3, h3);

    // ---- L4: GEMM 256->64 -> agg w/ relu+b4 (f32 out) ----
    k_gemm_mfma<32, 32><<<dim3(1, gy), T, 0, stream>>>(h3, wt4, dinv, nullptr, g4s, N_NODES, 256, 64, 0);
    k_agg<1, 1, 1, 0><<<aggB, T, 0, stream>>>(g4s, rowptr, csr, dinv, b4, h4);

    // ---- L5: GEMM 64->2, agg, log_softmax ----
    k_gemm2<<<nodeB, T, 0, stream>>>(h4, W5, dinv, g5s, N_NODES, 64);
    k_agg2<<<nodeB, T, 0, stream>>>(g5s, rowptr, csr, dinv, lgt);
    k_final<<<nodeB, T, 0, stream>>>(lgt, b5, out, N_NODES);
}

// Round 14
// 620.759 us; speedup vs baseline: 1.1346x; 1.1346x over previous
//
#include <hip/hip_runtime.h>
#include <math.h>

#define N_NODES 50000
#define N_EDGES 400000

typedef __bf16 bf16x8 __attribute__((ext_vector_type(8)));
typedef float f32x4 __attribute__((ext_vector_type(4)));

// ---- split-precision helpers: f32 <-> (hi bf16 | lo bf16) packed in u32 ----
__device__ __forceinline__ unsigned bf16_rne(float v) {
    unsigned u = __float_as_uint(v);
    return (u + 0x7FFFu + ((u >> 16) & 1u)) >> 16;
}
__device__ __forceinline__ unsigned pack_split(float v) {
    unsigned hi = bf16_rne(v);
    float hif = __uint_as_float(hi << 16);
    unsigned lo = bf16_rne(v - hif);
    return (hi << 16) | lo;
}
__device__ __forceinline__ float unpack_ps(unsigned w) {
    return __uint_as_float(w & 0xFFFF0000u) + __uint_as_float(w << 16);
}

// ================= CSR build =================
__global__ void k_zero_i(int* __restrict__ p, int n) {
    int i = blockIdx.x * blockDim.x + threadIdx.x;
    if (i < n) p[i] = 0;
}

__global__ void k_count(const int* __restrict__ dst, int* __restrict__ cnt) {
    int e = blockIdx.x * blockDim.x + threadIdx.x;
    if (e < N_EDGES) atomicAdd(&cnt[dst[e]], 1);
}

// ---- parallel 2-level scan (replaces 93us single-block k_scan) ----
// pass 1: per-block exclusive scan (1024/block) + block totals
__global__ __launch_bounds__(1024) void k_scan1(const int* __restrict__ cnt,
                                                int* __restrict__ loc,
                                                int* __restrict__ part, int n) {
    __shared__ int sm[1024];
    const int tid = threadIdx.x;
    const int i = blockIdx.x * 1024 + tid;
    int v = (i < n) ? cnt[i] : 0;
    sm[tid] = v;
    __syncthreads();
    for (int off = 1; off < 1024; off <<= 1) {
        int t = (tid >= off) ? sm[tid - off] : 0;
        __syncthreads();
        sm[tid] += t;
        __syncthreads();
    }
    if (i < n) loc[i] = sm[tid] - v;              // exclusive within block
    if (tid == 1023) part[blockIdx.x] = sm[1023]; // block total
}

// pass 2: scan the (<=64) block totals, single tiny block
__global__ void k_scan2(int* __restrict__ part, int* __restrict__ total, int nb) {
    __shared__ int sm[64];
    const int tid = threadIdx.x;
    int v = (tid < nb) ? part[tid] : 0;
    sm[tid] = v;
    __syncthreads();
    for (int off = 1; off < 64; off <<= 1) {
        int t = (tid >= off) ? sm[tid - off] : 0;
        __syncthreads();
        sm[tid] += t;
        __syncthreads();
    }
    if (tid < nb) part[tid] = sm[tid] - v;        // exclusive
    if (tid == 63) *total = sm[63];
}

// pass 3: combine -> rowptr, cursor (copy folded in), dinv
__global__ void k_scan3(const int* __restrict__ cnt, const int* __restrict__ loc,
                        const int* __restrict__ part, const int* __restrict__ total,
                        int* __restrict__ rowptr, int* __restrict__ cursor,
                        float* __restrict__ dinv, int n) {
    int i = blockIdx.x * blockDim.x + threadIdx.x;
    if (i < n) {
        int r = loc[i] + part[i >> 10];
        rowptr[i] = r;
        cursor[i] = r;
        dinv[i] = rsqrtf((float)(cnt[i] + 1));
    }
    if (i == 0) rowptr[n] = *total;
}

__global__ void k_fill(const int* __restrict__ src, const int* __restrict__ dst,
                       int* __restrict__ cursor, int* __restrict__ csr) {
    int e = blockIdx.x * blockDim.x + threadIdx.x;
    if (e >= N_EDGES) return;
    int d = dst[e];
    int pos = atomicAdd(&cursor[d], 1);
    csr[pos] = src[e];
}

// ================= weight prep: W[K][N] f32 -> Wt[N][K] packed =================
__global__ void k_wprep(const float* __restrict__ W, unsigned* __restrict__ Wtp, int K, int N) {
    int i = blockIdx.x * blockDim.x + threadIdx.x;
    if (i >= K * N) return;
    int k = i / N, n = i % N;
    Wtp[(size_t)n * K + k] = pack_split(W[i]);
}

// ================= xs = dinv[i] * x (f32) =================
__global__ void k_rowscale(const float* __restrict__ x, const float* __restrict__ dinv,
                           float* __restrict__ xs) {
    int idx = blockIdx.x * blockDim.x + threadIdx.x;
    if (idx >= N_NODES * 32) return;
    int i = idx >> 5;
    float4 v = ((const float4*)x)[idx];
    float s = dinv[i];
    v.x *= s; v.y *= s; v.z *= s; v.w *= s;
    ((float4*)xs)[idx] = v;
}

// ================= CSR aggregation =================
template <int VEC, int MODE, int INP, int OUTP>
__global__ __launch_bounds__(256) void k_agg(
    const void* __restrict__ gv, const int* __restrict__ rowptr,
    const int* __restrict__ csr, const float* __restrict__ dinv,
    const float* __restrict__ bias, void* __restrict__ ov)
{
    constexpr int W = 64 * VEC;
    const int wave = threadIdx.x >> 6, lane = threadIdx.x & 63;
    const int node = blockIdx.x * 4 + wave;
    if (node >= N_NODES) return;
    const int col = lane * VEC;

    float acc[VEC];
#pragma unroll
    for (int v = 0; v < VEC; ++v) acc[v] = 0.f;

    auto fetch_add = [&](int r) {
        if constexpr (INP) {
            const unsigned* p = (const unsigned*)gv + (size_t)r * W + col;
            if constexpr (VEC == 4) {
                uint4 t = *(const uint4*)p;
                acc[0] += unpack_ps(t.x); acc[1] += unpack_ps(t.y);
                acc[2] += unpack_ps(t.z); acc[3] += unpack_ps(t.w);
            } else if constexpr (VEC == 2) {
                uint2 t = *(const uint2*)p;
                acc[0] += unpack_ps(t.x); acc[1] += unpack_ps(t.y);
            } else acc[0] += unpack_ps(*p);
        } else {
            const float* p = (const float*)gv + (size_t)r * W + col;
            if constexpr (VEC == 4) {
                float4 t = *(const float4*)p;
                acc[0] += t.x; acc[1] += t.y; acc[2] += t.z; acc[3] += t.w;
            } else if constexpr (VEC == 2) {
                float2 t = *(const float2*)p;
                acc[0] += t.x; acc[1] += t.y;
            } else acc[0] += *(const float*)p;
        }
    };

    fetch_add(node);
    const int beg = rowptr[node], end = rowptr[node + 1];
    for (int j = beg; j < end; ++j) fetch_add(csr[j]);

    const float sc = dinv[node];
    float r[VEC];
#pragma unroll
    for (int v = 0; v < VEC; ++v) {
        float t = sc * acc[v];
        if (MODE == 1) t = fmaxf(t + bias[col + v], 0.f);
        r[v] = t;
    }
    if constexpr (OUTP) {
        unsigned* po = (unsigned*)ov + (size_t)node * W + col;
        if constexpr (VEC == 4)
            *(uint4*)po = make_uint4(pack_split(r[0]), pack_split(r[1]), pack_split(r[2]), pack_split(r[3]));
        else if constexpr (VEC == 2)
            *(uint2*)po = make_uint2(pack_split(r[0]), pack_split(r[1]));
        else *po = pack_split(r[0]);
    } else {
        float* po = (float*)ov + (size_t)node * W + col;
        if constexpr (VEC == 4) *(float4*)po = make_float4(r[0], r[1], r[2], r[3]);
        else if constexpr (VEC == 2) *(float2*)po = make_float2(r[0], r[1]);
        else *po = r[0];
    }
}

__global__ void k_agg2(const float* __restrict__ g, const int* __restrict__ rowptr,
                       const int* __restrict__ csr, const float* __restrict__ dinv,
                       float* __restrict__ o) {
    int i = blockIdx.x * blockDim.x + threadIdx.x;
    if (i >= N_NODES) return;
    float2 a = *(const float2*)&g[2 * (size_t)i];
    int beg = rowptr[i], end = rowptr[i + 1];
    for (int j = beg; j < end; ++j) {
        int s = csr[j];
        float2 t = *(const float2*)&g[2 * (size_t)s];
        a.x += t.x; a.y += t.y;
    }
    float sc = dinv[i];
    o[2 * (size_t)i + 0] = sc * a.x;
    o[2 * (size_t)i + 1] = sc * a.y;
}

// ================= split-bf16 MFMA GEMM, 2-phase pipelined =================
// A (packed [M][K]) @ Wt (packed [N][K]) -> Gp (packed [M][N]).
// Block: BM=2*WM x BN=2*WN, 256 threads = 4 waves in 2x2; wave owns WM x WN.
// BK=32; hi*hi + hi*lo + lo*hi (f32-level accuracy).
// mode 0: dinv[r]*acc; 1: relu(acc+bias); 2: dinv[r]*relu(acc+bias)
template <int WM, int WN>
__global__ __launch_bounds__(256) void k_gemm_mfma(
    const unsigned* __restrict__ Ap, const unsigned* __restrict__ Wtp,
    const float* __restrict__ dinv, const float* __restrict__ bias,
    unsigned* __restrict__ Gp, int M, int K, int N, int mode)
{
    constexpr int BM = 2 * WM, BN = 2 * WN;
    constexpr int AF = WM / 16, BF = WN / 16;
    constexpr int ACH = BM / 32, BCH = BN / 32;
    constexpr int BUF = (2 * BM + 2 * BN) * 64;
    __shared__ char lds[2 * BUF];

    const int tid = threadIdx.x;
    const int m0 = blockIdx.y * BM;
    const int n0 = blockIdx.x * BN;
    const int wv = tid >> 6, l = tid & 63;
    const int wr = wv >> 1, wc = wv & 1;
    const int lr = l & 15, ls = l >> 4;

    int aoff[AF], boff[BF];
#pragma unroll
    for (int f = 0; f < AF; ++f) {
        int row = wr * WM + f * 16 + lr;
        aoff[f] = (row * 64 + ls * 16) ^ ((row & 7) << 4);
    }
#pragma unroll
    for (int j = 0; j < BF; ++j) {
        int row = wc * WN + j * 16 + lr;
        boff[j] = (row * 64 + ls * 16) ^ ((row & 7) << 4);
    }

    uint4 ra[ACH], rb[BCH];

    auto issue = [&](int kt) {
#pragma unroll
        for (int p = 0; p < ACH; ++p) {
            int c = p * 256 + tid;
            int row = c >> 3, c4 = (c & 7) << 2;
            int grow = m0 + row;
            ra[p] = make_uint4(0u, 0u, 0u, 0u);
            if (grow < M) ra[p] = *(const uint4*)&Ap[(size_t)grow * K + kt + c4];
        }
#pragma unroll
        for (int p = 0; p < BCH; ++p) {
            int c = p * 256 + tid;
            int row = c >> 3, c4 = (c & 7) << 2;
            rb[p] = *(const uint4*)&Wtp[(size_t)(n0 + row) * K + kt + c4];
        }
    };

    auto commit = [&](int buf) {
        char* Ahi = lds + buf * BUF;
        char* Alo = Ahi + BM * 64;
        char* Bhi = Alo + BM * 64;
        char* Blo = Bhi + BN * 64;
#pragma unroll
        for (int p = 0; p < ACH; ++p) {
            int c = p * 256 + tid;
            int row = c >> 3, c4 = (c & 7) << 2;
            uint4 w = ra[p];
            ushort4 hi, lo;
            hi.x = w.x >> 16; lo.x = w.x & 0xFFFFu;
            hi.y = w.y >> 16; lo.y = w.y & 0xFFFFu;
            hi.z = w.z >> 16; lo.z = w.z & 0xFFFFu;
            hi.w = w.w >> 16; lo.w = w.w & 0xFFFFu;
            int off = (row * 64 + c4 * 2) ^ ((row & 7) << 4);
            *(ushort4*)(Ahi + off) = hi;
            *(ushort4*)(Alo + off) = lo;
        }
#pragma unroll
        for (int p = 0; p < BCH; ++p) {
            int c = p * 256 + tid;
            int row = c >> 3, c4 = (c & 7) << 2;
            uint4 w = rb[p];
            ushort4 hi, lo;
            hi.x = w.x >> 16; lo.x = w.x & 0xFFFFu;
            hi.y = w.y >> 16; lo.y = w.y & 0xFFFFu;
            hi.z = w.z >> 16; lo.z = w.z & 0xFFFFu;
            hi.w = w.w >> 16; lo.w = w.w & 0xFFFFu;
            int off = (row * 64 + c4 * 2) ^ ((row & 7) << 4);
            *(ushort4*)(Bhi + off) = hi;
            *(ushort4*)(Blo + off) = lo;
        }
    };

    f32x4 acc[AF][BF] = {};
    const int nt = K / 32;

    issue(0);
    commit(0);
    __syncthreads();
    int cur = 0;

    for (int t = 0; t < nt; ++t) {
        if (t + 1 < nt) issue((t + 1) * 32);

        const char* base = lds + cur * BUF;
        bf16x8 ah[AF], al[AF], bh[BF], bl[BF];
#pragma unroll
        for (int f = 0; f < AF; ++f) {
            ah[f] = *(const bf16x8*)(base + aoff[f]);
            al[f] = *(const bf16x8*)(base + BM * 64 + aoff[f]);
        }
#pragma unroll
        for (int j = 0; j < BF; ++j) {
            bh[j] = *(const bf16x8*)(base + 2 * BM * 64 + boff[j]);
            bl[j] = *(const bf16x8*)(base + 2 * BM * 64 + BN * 64 + boff[j]);
        }
#pragma unroll
        for (int f = 0; f < AF; ++f)
#pragma unroll
            for (int j = 0; j < BF; ++j) {
                acc[f][j] = __builtin_amdgcn_mfma_f32_16x16x32_bf16(ah[f], bh[j], acc[f][j], 0, 0, 0);
                acc[f][j] = __builtin_amdgcn_mfma_f32_16x16x32_bf16(ah[f], bl[j], acc[f][j], 0, 0, 0);
                acc[f][j] = __builtin_amdgcn_mfma_f32_16x16x32_bf16(al[f], bh[j], acc[f][j], 0, 0, 0);
            }

        if (t + 1 < nt) {
            commit(cur ^ 1);
            __syncthreads();
            cur ^= 1;
        }
    }

#pragma unroll
    for (int f = 0; f < AF; ++f)
#pragma unroll
        for (int j = 0; j < BF; ++j) {
            int col = n0 + wc * WN + j * 16 + lr;
            float bc = (mode >= 1) ? bias[col] : 0.f;
#pragma unroll
            for (int reg = 0; reg < 4; ++reg) {
                int r = m0 + wr * WM + f * 16 + ls * 4 + reg;
                if (r < M) {
                    float t = acc[f][j][reg];
                    if (mode == 0)      t = dinv[r] * t;
                    else if (mode == 1) t = fmaxf(t + bc, 0.f);
                    else                t = dinv[r] * fmaxf(t + bc, 0.f);
                    Gp[(size_t)r * N + col] = pack_split(t);
                }
            }
        }
}

// ================= last-layer GEMM: K=64, N=2, f32 =================
__global__ void k_gemm2(const float* __restrict__ A, const float* __restrict__ W,
                        const float* __restrict__ dinv, float* __restrict__ G, int M, int K)
{
    int i = blockIdx.x * blockDim.x + threadIdx.x;
    if (i >= M) return;
    float a0 = 0.f, a1 = 0.f;
    for (int k = 0; k < K; k += 4) {
        float4 a = *(const float4*)&A[(size_t)i * K + k];
        a0 += a.x * W[(k + 0) * 2 + 0] + a.y * W[(k + 1) * 2 + 0]
            + a.z * W[(k + 2) * 2 + 0] + a.w * W[(k + 3) * 2 + 0];
        a1 += a.x * W[(k + 0) * 2 + 1] + a.y * W[(k + 1) * 2 + 1]
            + a.z * W[(k + 2) * 2 + 1] + a.w * W[(k + 3) * 2 + 1];
    }
    float s = dinv[i];
    G[2 * (size_t)i + 0] = s * a0;
    G[2 * (size_t)i + 1] = s * a1;
}

// ================= final: logits + b5 -> log_softmax =================
__global__ void k_final(const float* __restrict__ lg, const float* __restrict__ bias,
                        float* __restrict__ out, int M)
{
    int i = blockIdx.x * blockDim.x + threadIdx.x;
    if (i >= M) return;
    float o0 = lg[2 * (size_t)i + 0] + bias[0];
    float o1 = lg[2 * (size_t)i + 1] + bias[1];
    float m = fmaxf(o0, o1);
    float lse = m + logf(expf(o0 - m) + expf(o1 - m));
    out[2 * (size_t)i + 0] = o0 - lse;
    out[2 * (size_t)i + 1] = o1 - lse;
}

extern "C" void kernel_launch(void* const* d_in, const int* in_sizes, int n_in,
                              void* d_out, int out_size, void* d_ws, size_t ws_size,
                              hipStream_t stream) {
    const float* x   = (const float*)d_in[0];
    const int*   ei  = (const int*)d_in[1];
    const int*   src = ei;
    const int*   dst = ei + N_EDGES;
    const float* W1 = (const float*)d_in[2];  const float* b1 = (const float*)d_in[3];
    const float* W2 = (const float*)d_in[4];  const float* b2 = (const float*)d_in[5];
    const float* W3 = (const float*)d_in[6];  const float* b3 = (const float*)d_in[7];
    const float* W4 = (const float*)d_in[8];  const float* b4 = (const float*)d_in[9];
    const float* W5 = (const float*)d_in[10]; const float* b5 = (const float*)d_in[11];
    float* out = (float*)d_out;

    char* ws = (char*)d_ws;
    float*    dinv   = (float*)(ws + 0);
    int*      cnt    = (int*)(ws + 256 * 1024);
    int*      rowptr = (int*)(ws + 512 * 1024);
    int*      cursor = (int*)(ws + 768 * 1024);
    int*      csr    = (int*)(ws + 1024 * 1024);          // 1.6MB, ends 2.6M
    int*      part   = (int*)(ws + 2700 * 1024);          // 64 ints
    int*      total  = (int*)(ws + 2702 * 1024);          // 1 int
    unsigned* wt1 = (unsigned*)(ws + 3 * 1024 * 1024);
    unsigned* wt2 = wt1 + 128 * 256;
    unsigned* wt3 = wt2 + 256 * 512;
    unsigned* wt4 = wt3 + 512 * 256;                      // ends ~4.25M
    int*      loc    = (int*)(ws + 5 * 1024 * 1024);      // 200KB scan scratch

    char* D = ws + 6 * 1024 * 1024;
    float*    xs   = (float*)D;                                    // [50000][128] f32
    unsigned* aggx = (unsigned*)(D + (size_t)N_NODES * 128 * 4);   // [50000][128] packed
    unsigned* h1s  = (unsigned*)(D + (size_t)N_NODES * 512 * 4);   // R1: [50000][256]
    unsigned* a2   = (unsigned*)(D + (size_t)N_NODES * 768 * 4);   // R2: [50000][256]
    unsigned* h2   = (unsigned*)D;                                 // R0: [50000][512]
    unsigned* g3s  = h1s;
    unsigned* h3   = a2;
    unsigned* g4s  = (unsigned*)D;                                 // [50000][64]
    float*    h4   = (float*)(D + (size_t)N_NODES * 64 * 4);       // [50000][64] f32
    float*    g5s  = (float*)(D + (size_t)N_NODES * 128 * 4);      // [50000][2]
    float*    lgt  = (float*)(D + (size_t)N_NODES * 132 * 4);      // [50000][2]

    const int T = 256;
    const int nodeB = (N_NODES + T - 1) / T;
    const int edgeB = (N_EDGES + T - 1) / T;
    const int aggB  = (N_NODES + 3) / 4;
    const int gy    = (N_NODES + 63) / 64;
    const int scanB = (N_NODES + 1023) / 1024;   // 49

    // ---- CSR + dinv + weight prep ----
    k_zero_i<<<nodeB, T, 0, stream>>>(cnt, N_NODES);
    k_count<<<edgeB, T, 0, stream>>>(dst, cnt);
    k_scan1<<<scanB, 1024, 0, stream>>>(cnt, loc, part, N_NODES);
    k_scan2<<<1, 64, 0, stream>>>(part, total, scanB);
    k_scan3<<<nodeB, T, 0, stream>>>(cnt, loc, part, total, rowptr, cursor, dinv, N_NODES);
    k_fill<<<edgeB, T, 0, stream>>>(src, dst, cursor, csr);
    k_wprep<<<(128 * 256 + T - 1) / T, T, 0, stream>>>(W1, wt1, 128, 256);
    k_wprep<<<(256 * 512 + T - 1) / T, T, 0, stream>>>(W2, wt2, 256, 512);
    k_wprep<<<(512 * 256 + T - 1) / T, T, 0, stream>>>(W3, wt3, 512, 256);
    k_wprep<<<(256 * 64 + T - 1) / T, T, 0, stream>>>(W4, wt4, 256, 64);

    // ---- L1: agg(128) -> GEMM 128->256, h1s = dinv*relu(+b1) ----
    k_rowscale<<<(N_NODES * 32 + T - 1) / T, T, 0, stream>>>(x, dinv, xs);
    k_agg<2, 0, 0, 1><<<aggB, T, 0, stream>>>(xs, rowptr, csr, dinv, nullptr, aggx);
    k_gemm_mfma<32, 64><<<dim3(2, gy), T, 0, stream>>>(aggx, wt1, dinv, b1, h1s, N_NODES, 128, 256, 2);

    // ---- L2: agg(256) -> GEMM 256->512, h2 = relu(+b2) ----
    k_agg<4, 0, 1, 1><<<aggB, T, 0, stream>>>(h1s, rowptr, csr, dinv, nullptr, a2);
    k_gemm_mfma<32, 64><<<dim3(4, gy), T, 0, stream>>>(a2, wt2, dinv, b2, h2, N_NODES, 256, 512, 1);

    // ---- L3: GEMM 512->256 (g3s = dinv*acc) -> agg w/ relu+b3 ----
    k_gemm_mfma<32, 64><<<dim3(2, gy), T, 0, stream>>>(h2, wt3, dinv, nullptr, g3s, N_NODES, 512, 256, 0);
    k_agg<4, 1, 1, 1><<<aggB, T, 0, stream>>>(g3s, rowptr, csr, dinv, b3, h3);

    // ---- L4: GEMM 256->64 -> agg w/ relu+b4 (f32 out) ----
    k_gemm_mfma<32, 32><<<dim3(1, gy), T, 0, stream>>>(h3, wt4, dinv, nullptr, g4s, N_NODES, 256, 64, 0);
    k_agg<1, 1, 1, 0><<<aggB, T, 0, stream>>>(g4s, rowptr, csr, dinv, b4, h4);

    // ---- L5: GEMM 64->2, agg, log_softmax ----
    k_gemm2<<<nodeB, T, 0, stream>>>(h4, W5, dinv, g5s, N_NODES, 64);
    k_agg2<<<nodeB, T, 0, stream>>>(g5s, rowptr, csr, dinv, lgt);
    k_final<<<nodeB, T, 0, stream>>>(lgt, b5, out, N_NODES);
}